// Round 1
// baseline (3346.822 us; speedup 1.0000x reference)
//
#include <hip/hip_runtime.h>

#define HIDDEN 128
#define ZDIM 56
#define NLAYERS 3
#define NGRAPHS 1024

// ---------------- GEMM: C[n x 128] = act(X[n x K] @ W[K x 128] (+ bias)) ----------------
// Block: 256 threads -> 32 rows x 128 cols tile; per-thread 4x4 register tile.
template<int K, bool RELU, bool BIAS>
__global__ __launch_bounds__(256)
void gemm128(const float* __restrict__ X, const float* __restrict__ W,
             const float* __restrict__ bias, float* __restrict__ C, int n)
{
    constexpr int KC = (K < 64) ? K : 64;
    __shared__ float sW[KC][HIDDEN];
    __shared__ float sX[32][KC];

    const int tid  = threadIdx.x;
    const int row0 = blockIdx.x * 32;
    const int rows = min(32, n - row0);
    if (rows <= 0) return;
    const int c0 = (tid & 31) * 4;
    const int r0 = (tid >> 5) * 4;

    float acc[4][4];
#pragma unroll
    for (int i = 0; i < 4; ++i)
#pragma unroll
        for (int j = 0; j < 4; ++j) acc[i][j] = 0.f;

    for (int kc = 0; kc < K; kc += KC) {
        __syncthreads();
        for (int i = tid; i < KC * HIDDEN; i += 256) {
            int k = i >> 7, c = i & 127;
            sW[k][c] = W[(size_t)(kc + k) * HIDDEN + c];
        }
        for (int i = tid; i < rows * KC; i += 256) {
            int r = i / KC, k = i % KC;
            sX[r][k] = X[(size_t)(row0 + r) * K + kc + k];
        }
        __syncthreads();
#pragma unroll 4
        for (int k = 0; k < KC; ++k) {
            float wv[4];
            *(float4*)wv = *(const float4*)&sW[k][c0];
#pragma unroll
            for (int i = 0; i < 4; ++i) {
                float xv = sX[r0 + i][k];
#pragma unroll
                for (int j = 0; j < 4; ++j) acc[i][j] += xv * wv[j];
            }
        }
    }
#pragma unroll
    for (int i = 0; i < 4; ++i) {
        if (r0 + i < rows) {
            float4 out;
            float* o = (float*)&out;
#pragma unroll
            for (int j = 0; j < 4; ++j) {
                float v = acc[i][j];
                if (BIAS) v += bias[c0 + j];
                if (RELU) v = fmaxf(v, 0.f);
                o[j] = v;
            }
            *(float4*)&C[(size_t)(row0 + r0 + i) * HIDDEN + c0] = out;
        }
    }
}

// ---------------- scatter: AG[dst] += relu(A[dst] + B[src] + mb) ----------------
// 8 edges/block, 32 threads/edge, float4 per thread.
__global__ __launch_bounds__(256)
void scatter_msg(const float* __restrict__ A, const float* __restrict__ B,
                 const float* __restrict__ mb,
                 const int* __restrict__ src, const int* __restrict__ dst,
                 float* __restrict__ AG, int E)
{
    const int tid = threadIdx.x;
    const int e = blockIdx.x * 8 + (tid >> 5);
    if (e >= E) return;
    const int f = (tid & 31) * 4;
    const int s = src[e], d = dst[e];
    float4 a = *(const float4*)&A[(size_t)d * HIDDEN + f];
    float4 b = *(const float4*)&B[(size_t)s * HIDDEN + f];
    float4 m = *(const float4*)&mb[f];
    float* ag = &AG[(size_t)d * HIDDEN + f];
    atomicAdd(ag + 0, fmaxf(a.x + b.x + m.x, 0.f));
    atomicAdd(ag + 1, fmaxf(a.y + b.y + m.y, 0.f));
    atomicAdd(ag + 2, fmaxf(a.z + b.z + m.z, 0.f));
    atomicAdd(ag + 3, fmaxf(a.w + b.w + m.w, 0.f));
}

// ---------------- pooling ----------------
__global__ __launch_bounds__(256)
void pool_sum(const float* __restrict__ H, const int* __restrict__ batch,
              float* __restrict__ PSUM, float* __restrict__ PCNT, int n)
{
    const int v = blockIdx.x * 2 + (threadIdx.x >> 7);
    if (v >= n) return;
    const int f = threadIdx.x & 127;
    const int b = batch[v];
    atomicAdd(&PSUM[(size_t)b * HIDDEN + f], H[(size_t)v * HIDDEN + f]);
    if (f == 0) atomicAdd(&PCNT[b], 1.0f);
}

__global__ __launch_bounds__(256)
void pool_div(const float* __restrict__ PSUM, const float* __restrict__ PCNT,
              float* __restrict__ fused, int half)
{
    const int i = blockIdx.x * 256 + threadIdx.x;
    if (i >= NGRAPHS * HIDDEN) return;
    const int b = i >> 7, f = i & 127;
    const float c = fmaxf(PCNT[b], 1.0f);
    fused[(size_t)b * (2 * HIDDEN) + half * HIDDEN + f] = PSUM[i] / c;
}

// ---------------- head: mu / logvar from fused [1024 x 256] ----------------
__global__ __launch_bounds__(128)
void head_kernel(const float* __restrict__ fused,
                 const float* __restrict__ muw, const float* __restrict__ mub,
                 const float* __restrict__ lvw, const float* __restrict__ lvb,
                 float* __restrict__ mu, float* __restrict__ lv)
{
    __shared__ float sf[2 * HIDDEN];
    const int b = blockIdx.x;
    const int t = threadIdx.x;
    sf[t] = fused[(size_t)b * 256 + t];
    sf[t + 128] = fused[(size_t)b * 256 + t + 128];
    __syncthreads();
    if (t < ZDIM) {
        float accm = mub[t], accl = lvb[t];
        for (int k = 0; k < 2 * HIDDEN; ++k) {
            float fv = sf[k];
            accm += fv * muw[(size_t)k * ZDIM + t];
            accl += fv * lvw[(size_t)k * ZDIM + t];
        }
        mu[(size_t)b * ZDIM + t] = accm;
        lv[(size_t)b * ZDIM + t] = accl;
    }
}

extern "C" void kernel_launch(void* const* d_in, const int* in_sizes, int n_in,
                              void* d_out, int out_size, void* d_ws, size_t ws_size,
                              hipStream_t stream)
{
    const float* tree_x   = (const float*)d_in[0];
    const int*   tree_ei  = (const int*)d_in[1];
    const float* graph_x  = (const float*)d_in[2];
    const int*   graph_ei = (const int*)d_in[3];
    const int*   batch_t  = (const int*)d_in[4];
    const int*   batch_g  = (const int*)d_in[5];
    const float* t_proj_w = (const float*)d_in[6];
    const float* t_proj_b = (const float*)d_in[7];
    const float* t_msg_w  = (const float*)d_in[8];
    const float* t_msg_b  = (const float*)d_in[9];
    const float* t_lin_w  = (const float*)d_in[10];
    const float* t_lin_b  = (const float*)d_in[11];
    const float* g_proj_w = (const float*)d_in[12];
    const float* g_proj_b = (const float*)d_in[13];
    const float* g_msg_w  = (const float*)d_in[14];
    const float* g_msg_b  = (const float*)d_in[15];
    const float* g_lin_w  = (const float*)d_in[16];
    const float* g_lin_b  = (const float*)d_in[17];
    const float* mu_w     = (const float*)d_in[18];
    const float* mu_b     = (const float*)d_in[19];
    const float* lv_w     = (const float*)d_in[20];
    const float* lv_b     = (const float*)d_in[21];

    const int n_tree  = in_sizes[0] / 64;
    const int e_tree  = in_sizes[1] / 2;
    const int n_graph = in_sizes[2] / 32;
    const int e_graph = in_sizes[3] / 2;

    float* out    = (float*)d_out;
    float* mu_out = out;
    float* lv_out = out + (size_t)NGRAPHS * ZDIM;
    float* fused  = out + (size_t)2 * NGRAPHS * ZDIM;

    const size_t NB = (size_t)n_graph * HIDDEN;   // buffers sized for larger encoder
    float* P[3];
    P[0] = (float*)d_ws;
    P[1] = P[0] + NB;
    P[2] = P[1] + NB;
    float* PSUM = P[2] + NB;
    float* PCNT = PSUM + (size_t)NGRAPHS * HIDDEN;

    auto run_encoder = [&](const float* x, int Kin, int n, int E, const int* ei,
                           const int* batch,
                           const float* proj_w, const float* proj_b,
                           const float* msg_w, const float* msg_b,
                           const float* lin_w, const float* lin_b, int half) {
        const int gb = (n + 31) / 32;
        if (Kin == 64)
            gemm128<64, true, true><<<gb, 256, 0, stream>>>(x, proj_w, proj_b, P[0], n);
        else
            gemm128<32, true, true><<<gb, 256, 0, stream>>>(x, proj_w, proj_b, P[0], n);

        const int* src = ei;        // edge_index[0]
        const int* dst = ei + E;    // edge_index[1]

        for (int l = 0; l < NLAYERS; ++l) {
            const int hi = l % 3;
            const int ai = (l + 1) % 3;
            const int bi = (l + 2) % 3;
            const float* Wl = msg_w + (size_t)l * 2 * HIDDEN * HIDDEN;
            // A = h @ W_top (applies to dst / x_i), B = h @ W_bot (src / x_j)
            gemm128<128, false, false><<<gb, 256, 0, stream>>>(P[hi], Wl, nullptr, P[ai], n);
            gemm128<128, false, false><<<gb, 256, 0, stream>>>(P[hi], Wl + HIDDEN * HIDDEN, nullptr, P[bi], n);
            hipMemsetAsync(P[hi], 0, (size_t)n * HIDDEN * sizeof(float), stream);
            scatter_msg<<<(E + 7) / 8, 256, 0, stream>>>(P[ai], P[bi], msg_b + (size_t)l * HIDDEN,
                                                         src, dst, P[hi], E);
            gemm128<128, true, true><<<gb, 256, 0, stream>>>(P[hi], lin_w + (size_t)l * HIDDEN * HIDDEN,
                                                             lin_b + (size_t)l * HIDDEN, P[ai], n);
            // h now lives in P[(l+1)%3] == next iteration's P[hi]
        }
        // final h in P[NLAYERS % 3] == P[0]
        hipMemsetAsync(PSUM, 0, (size_t)NGRAPHS * HIDDEN * sizeof(float), stream);
        hipMemsetAsync(PCNT, 0, (size_t)NGRAPHS * sizeof(float), stream);
        pool_sum<<<(n + 1) / 2, 256, 0, stream>>>(P[0], batch, PSUM, PCNT, n);
        pool_div<<<(NGRAPHS * HIDDEN + 255) / 256, 256, 0, stream>>>(PSUM, PCNT, fused, half);
    };

    run_encoder(tree_x, 64, n_tree, e_tree, tree_ei, batch_t,
                t_proj_w, t_proj_b, t_msg_w, t_msg_b, t_lin_w, t_lin_b, 0);
    run_encoder(graph_x, 32, n_graph, e_graph, graph_ei, batch_g,
                g_proj_w, g_proj_b, g_msg_w, g_msg_b, g_lin_w, g_lin_b, 1);

    head_kernel<<<NGRAPHS, 128, 0, stream>>>(fused, mu_w, mu_b, lv_w, lv_b, mu_out, lv_out);
}

// Round 2
// 1758.400 us; speedup vs baseline: 1.9033x; 1.9033x over previous
//
#include <hip/hip_runtime.h>

#define HIDDEN 128
#define ZDIM 56
#define NLAYERS 3
#define NGRAPHS 1024

// ---------------- GEMM: C[n x 128] = act(X[n x K] @ W[K x 128] (+ bias)) ----------------
// Block: 256 threads -> 32 rows x 128 cols tile; per-thread 4x4 register tile.
// Inner loop k-blocked by 4 so both LDS operands are ds_read_b128 (compute-bound).
template<int K, bool RELU, bool BIAS>
__global__ __launch_bounds__(256)
void gemm128(const float* __restrict__ X, const float* __restrict__ W,
             const float* __restrict__ bias, float* __restrict__ C, int n)
{
    constexpr int KC = (K < 64) ? K : 64;
    __shared__ float sW[KC][HIDDEN];
    __shared__ float sX[32][KC];

    const int tid  = threadIdx.x;
    const int row0 = blockIdx.x * 32;
    const int rows = min(32, n - row0);
    if (rows <= 0) return;
    const int c0 = (tid & 31) * 4;
    const int r0 = (tid >> 5) * 4;

    float acc[4][4] = {};

    for (int kc = 0; kc < K; kc += KC) {
        __syncthreads();
        // stage W chunk (KC x 128) as float4
        for (int i = tid; i < KC * (HIDDEN / 4); i += 256) {
            int k = i >> 5, c4 = i & 31;
            ((float4*)sW[k])[c4] = ((const float4*)&W[(size_t)(kc + k) * HIDDEN])[c4];
        }
        // stage X chunk (rows x KC) as float4
        for (int i = tid; i < rows * (KC / 4); i += 256) {
            int r = i / (KC / 4), k4 = i % (KC / 4);
            ((float4*)sX[r])[k4] = ((const float4*)&X[(size_t)(row0 + r) * K + kc])[k4];
        }
        __syncthreads();
#pragma unroll
        for (int k = 0; k < KC; k += 4) {
            float4 w0 = *(const float4*)&sW[k + 0][c0];
            float4 w1 = *(const float4*)&sW[k + 1][c0];
            float4 w2 = *(const float4*)&sW[k + 2][c0];
            float4 w3 = *(const float4*)&sW[k + 3][c0];
#pragma unroll
            for (int i = 0; i < 4; ++i) {
                float4 xv = *(const float4*)&sX[r0 + i][k];
                acc[i][0] += xv.x * w0.x + xv.y * w1.x + xv.z * w2.x + xv.w * w3.x;
                acc[i][1] += xv.x * w0.y + xv.y * w1.y + xv.z * w2.y + xv.w * w3.y;
                acc[i][2] += xv.x * w0.z + xv.y * w1.z + xv.z * w2.z + xv.w * w3.z;
                acc[i][3] += xv.x * w0.w + xv.y * w1.w + xv.z * w2.w + xv.w * w3.w;
            }
        }
    }
#pragma unroll
    for (int i = 0; i < 4; ++i) {
        if (r0 + i < rows) {
            float4 out;
            float* o = (float*)&out;
#pragma unroll
            for (int j = 0; j < 4; ++j) {
                float v = acc[i][j];
                if (BIAS) v += bias[c0 + j];
                if (RELU) v = fmaxf(v, 0.f);
                o[j] = v;
            }
            *(float4*)&C[(size_t)(row0 + r0 + i) * HIDDEN + c0] = out;
        }
    }
}

// ---------------- CSR build ----------------
__global__ __launch_bounds__(256)
void hist_kernel(const int* __restrict__ idx, int* __restrict__ deg, int n)
{
    int i = blockIdx.x * 256 + threadIdx.x;
    if (i < n) atomicAdd(&deg[idx[i]], 1);
}

// exclusive scan, 1024 elems per block; block totals -> partial
__global__ __launch_bounds__(256)
void scan_stage1(const int* __restrict__ in, int* __restrict__ excl,
                 int* __restrict__ partial, int n)
{
    const int tid = threadIdx.x;
    const int base = blockIdx.x * 1024 + tid * 4;
    int v[4];
    int s = 0;
#pragma unroll
    for (int i = 0; i < 4; ++i) {
        int t = (base + i < n) ? in[base + i] : 0;
        v[i] = s; s += t;
    }
    __shared__ int warpsum[4];
    const int lane = tid & 63, wid = tid >> 6;
    int pre = s;
#pragma unroll
    for (int off = 1; off < 64; off <<= 1) {
        int t = __shfl_up(pre, off);
        if (lane >= off) pre += t;
    }
    if (lane == 63) warpsum[wid] = pre;
    __syncthreads();
    int wo = 0;
    for (int w = 0; w < wid; ++w) wo += warpsum[w];
    const int thread_excl = wo + pre - s;
#pragma unroll
    for (int i = 0; i < 4; ++i)
        if (base + i < n) excl[base + i] = thread_excl + v[i];
    if (partial && tid == 255) partial[blockIdx.x] = wo + pre;
}

__global__ __launch_bounds__(256)
void scan_stage2(int* __restrict__ partial, int nb)
{
    __shared__ int tmp[256];
    const int tid = threadIdx.x;
    int v = (tid < nb) ? partial[tid] : 0;
    tmp[tid] = v;
    __syncthreads();
    for (int off = 1; off < 256; off <<= 1) {
        int t = (tid >= off) ? tmp[tid - off] : 0;
        __syncthreads();
        tmp[tid] += t;
        __syncthreads();
    }
    if (tid < nb) partial[tid] = tmp[tid] - v;   // exclusive
}

__global__ __launch_bounds__(256)
void scan_stage3(int* __restrict__ excl, const int* __restrict__ partial, int n)
{
    const int base = blockIdx.x * 1024 + threadIdx.x * 4;
    const int p = partial[blockIdx.x];
#pragma unroll
    for (int i = 0; i < 4; ++i)
        if (base + i < n) excl[base + i] += p;
}

__global__ __launch_bounds__(256)
void csr_fill(const int* __restrict__ src, const int* __restrict__ dst,
              const int* __restrict__ rowptr, int* __restrict__ cursor,
              int* __restrict__ csr_src, int E)
{
    int e = blockIdx.x * 256 + threadIdx.x;
    if (e >= E) return;
    int d = dst[e];
    int pos = atomicAdd(&cursor[d], 1);
    csr_src[rowptr[d] + pos] = src[e];
}

// ---------------- gather: AG[v] = sum_{e: dst=v} relu(A[v] + B[src_e] + mb) ----------------
// 8 nodes/block, 32 lanes/node, float4 per lane.
__global__ __launch_bounds__(256)
void gather_msg(const float* __restrict__ A, const float* __restrict__ B,
                const float* __restrict__ mb,
                const int* __restrict__ rowptr, const int* __restrict__ deg,
                const int* __restrict__ csr_src,
                float* __restrict__ AG, int n)
{
    const int v = blockIdx.x * 8 + (threadIdx.x >> 5);
    if (v >= n) return;
    const int f = (threadIdx.x & 31) * 4;
    float4 a = *(const float4*)&A[(size_t)v * HIDDEN + f];
    float4 m = *(const float4*)&mb[f];
    const float ax = a.x + m.x, ay = a.y + m.y, az = a.z + m.z, aw = a.w + m.w;
    float4 acc = {0.f, 0.f, 0.f, 0.f};
    const int start = rowptr[v];
    const int cnt = deg[v];
    for (int i = 0; i < cnt; ++i) {
        int s = csr_src[start + i];
        float4 b = *(const float4*)&B[(size_t)s * HIDDEN + f];
        acc.x += fmaxf(ax + b.x, 0.f);
        acc.y += fmaxf(ay + b.y, 0.f);
        acc.z += fmaxf(az + b.z, 0.f);
        acc.w += fmaxf(aw + b.w, 0.f);
    }
    *(float4*)&AG[(size_t)v * HIDDEN + f] = acc;
}

// ---------------- pooling (batch sorted -> contiguous node ranges per graph) ----------------
__global__ __launch_bounds__(128)
void pool_mean(const float* __restrict__ H, const int* __restrict__ rp,
               const int* __restrict__ cnt, float* __restrict__ fused, int half)
{
    const int b = blockIdx.x;
    const int f = threadIdx.x;
    const int start = rp[b];
    const int c = cnt[b];
    float acc = 0.f;
    for (int i = 0; i < c; ++i) acc += H[(size_t)(start + i) * HIDDEN + f];
    fused[(size_t)b * (2 * HIDDEN) + half * HIDDEN + f] = acc / fmaxf((float)c, 1.0f);
}

// ---------------- head: mu / logvar from fused [1024 x 256] ----------------
__global__ __launch_bounds__(128)
void head_kernel(const float* __restrict__ fused,
                 const float* __restrict__ muw, const float* __restrict__ mub,
                 const float* __restrict__ lvw, const float* __restrict__ lvb,
                 float* __restrict__ mu, float* __restrict__ lv)
{
    __shared__ float sf[2 * HIDDEN];
    const int b = blockIdx.x;
    const int t = threadIdx.x;
    sf[t] = fused[(size_t)b * 256 + t];
    sf[t + 128] = fused[(size_t)b * 256 + t + 128];
    __syncthreads();
    if (t < ZDIM) {
        float accm = mub[t], accl = lvb[t];
        for (int k = 0; k < 2 * HIDDEN; ++k) {
            float fv = sf[k];
            accm += fv * muw[(size_t)k * ZDIM + t];
            accl += fv * lvw[(size_t)k * ZDIM + t];
        }
        mu[(size_t)b * ZDIM + t] = accm;
        lv[(size_t)b * ZDIM + t] = accl;
    }
}

extern "C" void kernel_launch(void* const* d_in, const int* in_sizes, int n_in,
                              void* d_out, int out_size, void* d_ws, size_t ws_size,
                              hipStream_t stream)
{
    const float* tree_x   = (const float*)d_in[0];
    const int*   tree_ei  = (const int*)d_in[1];
    const float* graph_x  = (const float*)d_in[2];
    const int*   graph_ei = (const int*)d_in[3];
    const int*   batch_t  = (const int*)d_in[4];
    const int*   batch_g  = (const int*)d_in[5];
    const float* t_proj_w = (const float*)d_in[6];
    const float* t_proj_b = (const float*)d_in[7];
    const float* t_msg_w  = (const float*)d_in[8];
    const float* t_msg_b  = (const float*)d_in[9];
    const float* t_lin_w  = (const float*)d_in[10];
    const float* t_lin_b  = (const float*)d_in[11];
    const float* g_proj_w = (const float*)d_in[12];
    const float* g_proj_b = (const float*)d_in[13];
    const float* g_msg_w  = (const float*)d_in[14];
    const float* g_msg_b  = (const float*)d_in[15];
    const float* g_lin_w  = (const float*)d_in[16];
    const float* g_lin_b  = (const float*)d_in[17];
    const float* mu_w     = (const float*)d_in[18];
    const float* mu_b     = (const float*)d_in[19];
    const float* lv_w     = (const float*)d_in[20];
    const float* lv_b     = (const float*)d_in[21];

    const int n_tree  = in_sizes[0] / 64;
    const int e_tree  = in_sizes[1] / 2;
    const int n_graph = in_sizes[2] / 32;
    const int e_graph = in_sizes[3] / 2;

    float* out    = (float*)d_out;
    float* mu_out = out;
    float* lv_out = out + (size_t)NGRAPHS * ZDIM;
    float* fused  = out + (size_t)2 * NGRAPHS * ZDIM;

    const size_t NB = (size_t)n_graph * HIDDEN;   // buffers sized for larger encoder
    float* P[3];
    P[0] = (float*)d_ws;
    P[1] = P[0] + NB;
    P[2] = P[1] + NB;
    int* deg     = (int*)(P[2] + NB);
    int* rowptr  = deg + n_graph;
    int* cursor  = rowptr + n_graph;
    int* csr_src = cursor + n_graph;
    int* partial = csr_src + e_graph;      // 256 ints
    int* degb    = partial + 256;          // NGRAPHS
    int* rpb     = degb + NGRAPHS;         // NGRAPHS

    auto run_encoder = [&](const float* x, int Kin, int n, int E, const int* ei,
                           const int* batch,
                           const float* proj_w, const float* proj_b,
                           const float* msg_w, const float* msg_b,
                           const float* lin_w, const float* lin_b, int half) {
        const int gb = (n + 31) / 32;
        const int nb = (n + 1023) / 1024;
        const int* src = ei;        // edge_index[0]  (x_j)
        const int* dst = ei + E;    // edge_index[1]  (x_i / aggregation target)

        // ---- CSR build (once per encoder) ----
        hipMemsetAsync(deg, 0, (size_t)n * sizeof(int), stream);
        hipMemsetAsync(cursor, 0, (size_t)n * sizeof(int), stream);
        hist_kernel<<<(E + 255) / 256, 256, 0, stream>>>(dst, deg, E);
        scan_stage1<<<nb, 256, 0, stream>>>(deg, rowptr, partial, n);
        scan_stage2<<<1, 256, 0, stream>>>(partial, nb);
        scan_stage3<<<nb, 256, 0, stream>>>(rowptr, partial, n);
        csr_fill<<<(E + 255) / 256, 256, 0, stream>>>(src, dst, rowptr, cursor, csr_src, E);

        // ---- batch ranges (batch is sorted) ----
        hipMemsetAsync(degb, 0, NGRAPHS * sizeof(int), stream);
        hist_kernel<<<(n + 255) / 256, 256, 0, stream>>>(batch, degb, n);
        scan_stage1<<<1, 256, 0, stream>>>(degb, rpb, nullptr, NGRAPHS);

        // ---- input projection ----
        if (Kin == 64)
            gemm128<64, true, true><<<gb, 256, 0, stream>>>(x, proj_w, proj_b, P[0], n);
        else
            gemm128<32, true, true><<<gb, 256, 0, stream>>>(x, proj_w, proj_b, P[0], n);

        for (int l = 0; l < NLAYERS; ++l) {
            const int hi = l % 3;
            const int ai = (l + 1) % 3;
            const int bi = (l + 2) % 3;
            const float* Wl = msg_w + (size_t)l * 2 * HIDDEN * HIDDEN;
            // A = h @ W_top (dst / x_i), B = h @ W_bot (src / x_j)
            gemm128<128, false, false><<<gb, 256, 0, stream>>>(P[hi], Wl, nullptr, P[ai], n);
            gemm128<128, false, false><<<gb, 256, 0, stream>>>(P[hi], Wl + HIDDEN * HIDDEN, nullptr, P[bi], n);
            // h (P[hi]) dead now; gather overwrites it fully (no memset needed)
            gather_msg<<<(n + 7) / 8, 256, 0, stream>>>(P[ai], P[bi], msg_b + (size_t)l * HIDDEN,
                                                        rowptr, deg, csr_src, P[hi], n);
            gemm128<128, true, true><<<gb, 256, 0, stream>>>(P[hi], lin_w + (size_t)l * HIDDEN * HIDDEN,
                                                             lin_b + (size_t)l * HIDDEN, P[ai], n);
            // h_next lives in P[(l+1)%3] == next iteration's P[hi]
        }
        // final h in P[0]
        pool_mean<<<NGRAPHS, 128, 0, stream>>>(P[0], rpb, degb, fused, half);
    };

    run_encoder(tree_x, 64, n_tree, e_tree, tree_ei, batch_t,
                t_proj_w, t_proj_b, t_msg_w, t_msg_b, t_lin_w, t_lin_b, 0);
    run_encoder(graph_x, 32, n_graph, e_graph, graph_ei, batch_g,
                g_proj_w, g_proj_b, g_msg_w, g_msg_b, g_lin_w, g_lin_b, 1);

    head_kernel<<<NGRAPHS, 128, 0, stream>>>(fused, mu_w, mu_b, lv_w, lv_b, mu_out, lv_out);
}

// Round 3
// 1134.902 us; speedup vs baseline: 2.9490x; 1.5494x over previous
//
#include <hip/hip_runtime.h>

#define HIDDEN 128
#define ZDIM 56
#define NLAYERS 3
#define NGRAPHS 1024

// ---------------- GEMM: C[n x TN] = act(X[n x K] @ W[K x TN] (+ bias)) ----------------
// Tile: 128 rows x TN cols, TH = 2*TN threads, 8x8 outputs/thread split into
// 2x2 quadrants of 4x4 (cols cg*4 and cg*4+TN/2, rows rg*4 and rg*4+64) so
// every LDS read is stride-1 ds_read_b128 (W) or a 32-lane broadcast (X).
// FUSEDW: W is the vertical concat [W_top; W_bot] of msg_w (each [128,128]
// row-major); output col c<128 uses W_top, c>=128 uses W_bot.
template<int K, int TN, bool RELU, bool BIAS, bool FUSEDW>
__global__ __launch_bounds__(2 * TN)
void gemm_rt(const float* __restrict__ X, const float* __restrict__ W,
             const float* __restrict__ bias, float* __restrict__ C, int n)
{
    constexpr int TH = 2 * TN;
    constexpr int KC = (K < 32) ? K : 32;
    constexpr int NCG = TN / 8;          // col groups
    __shared__ float sXT[KC][128];       // transposed X chunk
    __shared__ float sW[KC][TN];

    const int tid  = threadIdx.x;
    const int row0 = blockIdx.x * 128;
    const int rows = min(128, n - row0);
    if (rows <= 0) return;
    const int cg = tid % NCG;            // col group -> cols cg*4, cg*4+TN/2
    const int rg = tid / NCG;            // row group (0..15) -> rows rg*4, rg*4+64

    float acc[8][8] = {};

    for (int kc = 0; kc < K; kc += KC) {
        __syncthreads();
        // stage W chunk (KC x TN) as float4, stride-1
        for (int i = tid; i < KC * (TN / 4); i += TH) {
            int k = i / (TN / 4), c4 = i % (TN / 4);
            int c = c4 * 4;
            size_t g;
            if (FUSEDW) {
                g = (c < 128) ? (size_t)(kc + k) * 128 + c
                              : (size_t)16384 + (size_t)(kc + k) * 128 + (c - 128);
            } else {
                g = (size_t)(kc + k) * TN + c;
            }
            ((float4*)sW[k])[c4] = *(const float4*)&W[g];
        }
        // stage X chunk transposed: sXT[k][r] = X[row0+r][kc+k]
        for (int i = tid; i < (KC / 4) * 128; i += TH) {
            int r = i & 127, k4 = i >> 7;
            float4 v = {0.f, 0.f, 0.f, 0.f};
            if (r < rows) v = *(const float4*)&X[(size_t)(row0 + r) * K + kc + k4 * 4];
            sXT[k4 * 4 + 0][r] = v.x;
            sXT[k4 * 4 + 1][r] = v.y;
            sXT[k4 * 4 + 2][r] = v.z;
            sXT[k4 * 4 + 3][r] = v.w;
        }
        __syncthreads();
#pragma unroll 4
        for (int k = 0; k < KC; ++k) {
            float wv[8], xv[8];
            *(float4*)&wv[0] = *(const float4*)&sW[k][cg * 4];
            *(float4*)&wv[4] = *(const float4*)&sW[k][cg * 4 + TN / 2];
            *(float4*)&xv[0] = *(const float4*)&sXT[k][rg * 4];
            *(float4*)&xv[4] = *(const float4*)&sXT[k][rg * 4 + 64];
#pragma unroll
            for (int i = 0; i < 8; ++i)
#pragma unroll
                for (int j = 0; j < 8; ++j)
                    acc[i][j] += xv[i] * wv[j];
        }
    }
    // epilogue
#pragma unroll
    for (int i = 0; i < 8; ++i) {
        const int r = (i < 4) ? rg * 4 + i : 64 + rg * 4 + (i - 4);
        if (r < rows) {
            float* crow = &C[(size_t)(row0 + r) * TN];
#pragma unroll
            for (int half = 0; half < 2; ++half) {
                const int c = cg * 4 + half * (TN / 2);
                float4 outv;
                float* o = (float*)&outv;
#pragma unroll
                for (int j = 0; j < 4; ++j) {
                    float v = acc[i][half * 4 + j];
                    if (BIAS) v += bias[c + j];
                    if (RELU) v = fmaxf(v, 0.f);
                    o[j] = v;
                }
                *(float4*)&crow[c] = outv;
            }
        }
    }
}

// ---------------- CSR build ----------------
__global__ __launch_bounds__(256)
void hist_kernel(const int* __restrict__ idx, int* __restrict__ deg, int n)
{
    int i = blockIdx.x * 256 + threadIdx.x;
    if (i < n) atomicAdd(&deg[idx[i]], 1);
}

__global__ __launch_bounds__(256)
void scan_stage1(const int* __restrict__ in, int* __restrict__ excl,
                 int* __restrict__ partial, int n)
{
    const int tid = threadIdx.x;
    const int base = blockIdx.x * 1024 + tid * 4;
    int v[4];
    int s = 0;
#pragma unroll
    for (int i = 0; i < 4; ++i) {
        int t = (base + i < n) ? in[base + i] : 0;
        v[i] = s; s += t;
    }
    __shared__ int warpsum[4];
    const int lane = tid & 63, wid = tid >> 6;
    int pre = s;
#pragma unroll
    for (int off = 1; off < 64; off <<= 1) {
        int t = __shfl_up(pre, off);
        if (lane >= off) pre += t;
    }
    if (lane == 63) warpsum[wid] = pre;
    __syncthreads();
    int wo = 0;
    for (int w = 0; w < wid; ++w) wo += warpsum[w];
    const int thread_excl = wo + pre - s;
#pragma unroll
    for (int i = 0; i < 4; ++i)
        if (base + i < n) excl[base + i] = thread_excl + v[i];
    if (partial && tid == 255) partial[blockIdx.x] = wo + pre;
}

__global__ __launch_bounds__(256)
void scan_stage2(int* __restrict__ partial, int nb)
{
    __shared__ int tmp[256];
    const int tid = threadIdx.x;
    int v = (tid < nb) ? partial[tid] : 0;
    tmp[tid] = v;
    __syncthreads();
    for (int off = 1; off < 256; off <<= 1) {
        int t = (tid >= off) ? tmp[tid - off] : 0;
        __syncthreads();
        tmp[tid] += t;
        __syncthreads();
    }
    if (tid < nb) partial[tid] = tmp[tid] - v;   // exclusive
}

__global__ __launch_bounds__(256)
void scan_stage3(int* __restrict__ excl, const int* __restrict__ partial, int n)
{
    const int base = blockIdx.x * 1024 + threadIdx.x * 4;
    const int p = partial[blockIdx.x];
#pragma unroll
    for (int i = 0; i < 4; ++i)
        if (base + i < n) excl[base + i] += p;
}

__global__ __launch_bounds__(256)
void csr_fill(const int* __restrict__ src, const int* __restrict__ dst,
              const int* __restrict__ rowptr, int* __restrict__ cursor,
              int* __restrict__ csr_src, int E)
{
    int e = blockIdx.x * 256 + threadIdx.x;
    if (e >= E) return;
    int d = dst[e];
    int pos = atomicAdd(&cursor[d], 1);
    csr_src[rowptr[d] + pos] = src[e];
}

// ---------------- gather from fused AB buffer [n x 256] ----------------
// aggr[v] = sum_{e: dst=v} relu(AB[v][0:128] + AB[src_e][128:256] + mb)
__global__ __launch_bounds__(256)
void gather_msg(const float* __restrict__ AB, const float* __restrict__ mb,
                const int* __restrict__ rowptr, const int* __restrict__ deg,
                const int* __restrict__ csr_src,
                float* __restrict__ AG, int n)
{
    const int v = blockIdx.x * 8 + (threadIdx.x >> 5);
    if (v >= n) return;
    const int f = (threadIdx.x & 31) * 4;
    float4 a = *(const float4*)&AB[(size_t)v * 256 + f];
    float4 m = *(const float4*)&mb[f];
    const float ax = a.x + m.x, ay = a.y + m.y, az = a.z + m.z, aw = a.w + m.w;
    float4 acc = {0.f, 0.f, 0.f, 0.f};
    const int start = rowptr[v];
    const int cnt = deg[v];
    for (int i = 0; i < cnt; ++i) {
        int s = csr_src[start + i];
        float4 b = *(const float4*)&AB[(size_t)s * 256 + 128 + f];
        acc.x += fmaxf(ax + b.x, 0.f);
        acc.y += fmaxf(ay + b.y, 0.f);
        acc.z += fmaxf(az + b.z, 0.f);
        acc.w += fmaxf(aw + b.w, 0.f);
    }
    *(float4*)&AG[(size_t)v * HIDDEN + f] = acc;
}

// ---------------- pooling (batch sorted -> contiguous node ranges per graph) ----------------
__global__ __launch_bounds__(128)
void pool_mean(const float* __restrict__ H, const int* __restrict__ rp,
               const int* __restrict__ cnt, float* __restrict__ fused, int half)
{
    const int b = blockIdx.x;
    const int f = threadIdx.x;
    const int start = rp[b];
    const int c = cnt[b];
    float acc = 0.f;
    for (int i = 0; i < c; ++i) acc += H[(size_t)(start + i) * HIDDEN + f];
    fused[(size_t)b * (2 * HIDDEN) + half * HIDDEN + f] = acc / fmaxf((float)c, 1.0f);
}

// ---------------- head: mu / logvar from fused [1024 x 256] ----------------
__global__ __launch_bounds__(128)
void head_kernel(const float* __restrict__ fused,
                 const float* __restrict__ muw, const float* __restrict__ mub,
                 const float* __restrict__ lvw, const float* __restrict__ lvb,
                 float* __restrict__ mu, float* __restrict__ lv)
{
    __shared__ float sf[2 * HIDDEN];
    const int b = blockIdx.x;
    const int t = threadIdx.x;
    sf[t] = fused[(size_t)b * 256 + t];
    sf[t + 128] = fused[(size_t)b * 256 + t + 128];
    __syncthreads();
    if (t < ZDIM) {
        float accm = mub[t], accl = lvb[t];
        for (int k = 0; k < 2 * HIDDEN; ++k) {
            float fv = sf[k];
            accm += fv * muw[(size_t)k * ZDIM + t];
            accl += fv * lvw[(size_t)k * ZDIM + t];
        }
        mu[(size_t)b * ZDIM + t] = accm;
        lv[(size_t)b * ZDIM + t] = accl;
    }
}

extern "C" void kernel_launch(void* const* d_in, const int* in_sizes, int n_in,
                              void* d_out, int out_size, void* d_ws, size_t ws_size,
                              hipStream_t stream)
{
    const float* tree_x   = (const float*)d_in[0];
    const int*   tree_ei  = (const int*)d_in[1];
    const float* graph_x  = (const float*)d_in[2];
    const int*   graph_ei = (const int*)d_in[3];
    const int*   batch_t  = (const int*)d_in[4];
    const int*   batch_g  = (const int*)d_in[5];
    const float* t_proj_w = (const float*)d_in[6];
    const float* t_proj_b = (const float*)d_in[7];
    const float* t_msg_w  = (const float*)d_in[8];
    const float* t_msg_b  = (const float*)d_in[9];
    const float* t_lin_w  = (const float*)d_in[10];
    const float* t_lin_b  = (const float*)d_in[11];
    const float* g_proj_w = (const float*)d_in[12];
    const float* g_proj_b = (const float*)d_in[13];
    const float* g_msg_w  = (const float*)d_in[14];
    const float* g_msg_b  = (const float*)d_in[15];
    const float* g_lin_w  = (const float*)d_in[16];
    const float* g_lin_b  = (const float*)d_in[17];
    const float* mu_w     = (const float*)d_in[18];
    const float* mu_b     = (const float*)d_in[19];
    const float* lv_w     = (const float*)d_in[20];
    const float* lv_b     = (const float*)d_in[21];

    const int n_tree  = in_sizes[0] / 64;
    const int e_tree  = in_sizes[1] / 2;
    const int n_graph = in_sizes[2] / 32;
    const int e_graph = in_sizes[3] / 2;

    float* out    = (float*)d_out;
    float* mu_out = out;
    float* lv_out = out + (size_t)NGRAPHS * ZDIM;
    float* fused  = out + (size_t)2 * NGRAPHS * ZDIM;

    const size_t NB = (size_t)n_graph * HIDDEN;   // sized for larger encoder
    float* P0  = (float*)d_ws;                    // h / aggr   [n,128]
    float* PAB = P0 + NB;                         // fused A|B  [n,256]
    int* deg     = (int*)(PAB + 2 * NB);
    int* rowptr  = deg + n_graph;
    int* cursor  = rowptr + n_graph;
    int* csr_src = cursor + n_graph;
    int* partial = csr_src + e_graph;      // 256 ints
    int* degb    = partial + 256;          // NGRAPHS
    int* rpb     = degb + NGRAPHS;         // NGRAPHS

    auto run_encoder = [&](const float* x, int Kin, int n, int E, const int* ei,
                           const int* batch,
                           const float* proj_w, const float* proj_b,
                           const float* msg_w, const float* msg_b,
                           const float* lin_w, const float* lin_b, int half) {
        const int gb = (n + 127) / 128;
        const int nb = (n + 1023) / 1024;
        const int* src = ei;        // edge_index[0]  (x_j)
        const int* dst = ei + E;    // edge_index[1]  (x_i / aggregation target)

        // ---- CSR build ----
        hipMemsetAsync(deg, 0, (size_t)n * sizeof(int), stream);
        hipMemsetAsync(cursor, 0, (size_t)n * sizeof(int), stream);
        hist_kernel<<<(E + 255) / 256, 256, 0, stream>>>(dst, deg, E);
        scan_stage1<<<nb, 256, 0, stream>>>(deg, rowptr, partial, n);
        scan_stage2<<<1, 256, 0, stream>>>(partial, nb);
        scan_stage3<<<nb, 256, 0, stream>>>(rowptr, partial, n);
        csr_fill<<<(E + 255) / 256, 256, 0, stream>>>(src, dst, rowptr, cursor, csr_src, E);

        // ---- batch ranges (batch sorted) ----
        hipMemsetAsync(degb, 0, NGRAPHS * sizeof(int), stream);
        hist_kernel<<<(n + 255) / 256, 256, 0, stream>>>(batch, degb, n);
        scan_stage1<<<1, 256, 0, stream>>>(degb, rpb, nullptr, NGRAPHS);

        // ---- input projection ----
        if (Kin == 64)
            gemm_rt<64, 128, true, true, false><<<gb, 256, 0, stream>>>(x, proj_w, proj_b, P0, n);
        else
            gemm_rt<32, 128, true, true, false><<<gb, 256, 0, stream>>>(x, proj_w, proj_b, P0, n);

        for (int l = 0; l < NLAYERS; ++l) {
            const float* Wl = msg_w + (size_t)l * 2 * HIDDEN * HIDDEN;
            // AB = h @ [W_top | W_bot]  -> [n, 256]
            gemm_rt<128, 256, false, false, true><<<gb, 512, 0, stream>>>(P0, Wl, nullptr, PAB, n);
            // aggr (overwrites h)
            gather_msg<<<(n + 7) / 8, 256, 0, stream>>>(PAB, msg_b + (size_t)l * HIDDEN,
                                                        rowptr, deg, csr_src, P0, n);
            // h_next = relu(aggr @ lin + b), in place
            gemm_rt<128, 128, true, true, false><<<gb, 256, 0, stream>>>(
                P0, lin_w + (size_t)l * HIDDEN * HIDDEN, lin_b + (size_t)l * HIDDEN, P0, n);
        }
        pool_mean<<<NGRAPHS, 128, 0, stream>>>(P0, rpb, degb, fused, half);
    };

    run_encoder(tree_x, 64, n_tree, e_tree, tree_ei, batch_t,
                t_proj_w, t_proj_b, t_msg_w, t_msg_b, t_lin_w, t_lin_b, 0);
    run_encoder(graph_x, 32, n_graph, e_graph, graph_ei, batch_g,
                g_proj_w, g_proj_b, g_msg_w, g_msg_b, g_lin_w, g_lin_b, 1);

    head_kernel<<<NGRAPHS, 128, 0, stream>>>(fused, mu_w, mu_b, lv_w, lv_b, mu_out, lv_out);
}

// Round 4
// 938.371 us; speedup vs baseline: 3.5666x; 1.2094x over previous
//
#include <hip/hip_runtime.h>

#define HIDDEN 128
#define ZDIM 56
#define NLAYERS 3
#define NGRAPHS 1024

typedef __attribute__((ext_vector_type(8))) short short8v;
typedef __attribute__((ext_vector_type(4))) float float4v;

__device__ __forceinline__ ushort f2bf(float v) {
    union { float f; unsigned u; } x; x.f = v;
    unsigned r = x.u + 0x7fffu + ((x.u >> 16) & 1u);   // RNE
    return (ushort)(r >> 16);
}
__device__ __forceinline__ float bf2f(ushort h) {
    union { unsigned u; float f; } x; x.u = ((unsigned)h) << 16;
    return x.f;
}
__device__ __forceinline__ void split_bf(float v, ushort& hi, ushort& lo) {
    hi = f2bf(v);
    lo = f2bf(v - bf2f(hi));
}

// ============ split-bf16 MFMA GEMM: C[n x TN] = act(X[n x 128] @ W[128 x TN] (+bias)) ============
// X given as hi/lo bf16 planes [n][128]; W given TRANSPOSED as hi/lo [TN][128].
// Block 256 thr / 4 waves; tile M=64 (4 row-frags), wave w owns col-frags [w*CPW, (w+1)*CPW).
// LDS seg-major layout [seg][idx][8] -> all frag reads are 2-way-free ds_read_b128.
// 3 MFMAs per (hi,lo) pair: ah*bh + ah*bl + al*bh  (al*bl ~2^-18, dropped).
template<int TN, bool RELU, bool BIAS, bool OUTHILO>
__global__ __launch_bounds__(256)
void gemm_mfma(const ushort* __restrict__ Xhi, const ushort* __restrict__ Xlo,
               const ushort* __restrict__ WThi, const ushort* __restrict__ WTlo,
               const float* __restrict__ bias,
               float* __restrict__ Cf, ushort* __restrict__ Chi, ushort* __restrict__ Clo,
               int n)
{
    constexpr int K = 128;
    constexpr int CPW = TN / 64;                 // col frags per wave
    __shared__ ushort smem[4096 + 2 * TN * 32];  // sXh[4][64][8] sXl | sWh[4][TN][8] sWl
    ushort* sXh = smem;
    ushort* sXl = smem + 2048;
    ushort* sWh = smem + 4096;
    ushort* sWl = smem + 4096 + TN * 32;

    const int tid = threadIdx.x;
    const int w = tid >> 6, l = tid & 63;
    const int row0 = blockIdx.x * 64;
    if (row0 >= n) return;

    float4v acc[4][CPW];
#pragma unroll
    for (int i = 0; i < 4; ++i)
#pragma unroll
        for (int j = 0; j < CPW; ++j) {
            float4v z = {0.f, 0.f, 0.f, 0.f};
            acc[i][j] = z;
        }

    const int seg = l >> 4, lr = l & 15;

    for (int kc = 0; kc < K; kc += 32) {
        __syncthreads();
        // stage X: 2 planes x 4 seg x 64 rows, 16B cells
        for (int c = tid; c < 512; c += 256) {
            int plane = c >> 8, rem = c & 255, sg = rem >> 6, r = rem & 63;
            const ushort* srcp = plane ? Xlo : Xhi;
            ushort* dstp = plane ? sXl : sXh;
            short8v v = {0, 0, 0, 0, 0, 0, 0, 0};
            if (row0 + r < n)
                v = *(const short8v*)&srcp[(size_t)(row0 + r) * K + kc + sg * 8];
            *(short8v*)&dstp[sg * 512 + r * 8] = v;
        }
        // stage W: 2 planes x 4 seg x TN cols
        for (int c = tid; c < 8 * TN; c += 256) {
            int plane = (c >= 4 * TN);
            int rem = plane ? c - 4 * TN : c;
            int sg = rem / TN, col = rem % TN;
            const ushort* srcp = plane ? WTlo : WThi;
            ushort* dstp = plane ? sWl : sWh;
            *(short8v*)&dstp[sg * TN * 8 + col * 8] =
                *(const short8v*)&srcp[(size_t)col * K + kc + sg * 8];
        }
        __syncthreads();

        short8v ah[4], al[4];
#pragma unroll
        for (int i = 0; i < 4; ++i) {
            int off = seg * 512 + (i * 16 + lr) * 8;
            ah[i] = *(const short8v*)&sXh[off];
            al[i] = *(const short8v*)&sXl[off];
        }
#pragma unroll
        for (int j = 0; j < CPW; ++j) {
            int col = (w * CPW + j) * 16 + lr;
            int off = seg * TN * 8 + col * 8;
            short8v bh = *(const short8v*)&sWh[off];
            short8v bl = *(const short8v*)&sWl[off];
#pragma unroll
            for (int i = 0; i < 4; ++i) {
                acc[i][j] = __builtin_amdgcn_mfma_f32_16x16x32_bf16(ah[i], bh, acc[i][j], 0, 0, 0);
                acc[i][j] = __builtin_amdgcn_mfma_f32_16x16x32_bf16(ah[i], bl, acc[i][j], 0, 0, 0);
                acc[i][j] = __builtin_amdgcn_mfma_f32_16x16x32_bf16(al[i], bh, acc[i][j], 0, 0, 0);
            }
        }
    }

    // epilogue: D[row=(l>>4)*4+r][col=l&15] within each 16x16 frag
#pragma unroll
    for (int i = 0; i < 4; ++i) {
#pragma unroll
        for (int j = 0; j < CPW; ++j) {
            const int gcol = (w * CPW + j) * 16 + lr;
            const float bv = BIAS ? bias[gcol] : 0.f;
#pragma unroll
            for (int r = 0; r < 4; ++r) {
                const int grow = row0 + i * 16 + seg * 4 + r;
                if (grow < n) {
                    float v = acc[i][j][r] + bv;
                    if (RELU) v = fmaxf(v, 0.f);
                    if (OUTHILO) {
                        ushort hi, lo;
                        split_bf(v, hi, lo);
                        Chi[(size_t)grow * TN + gcol] = hi;
                        Clo[(size_t)grow * TN + gcol] = lo;
                    } else {
                        Cf[(size_t)grow * TN + gcol] = v;
                    }
                }
            }
        }
    }
}

// ============ f32 vector GEMM for input projection (K=32/64), TN=128 ============
template<int K, bool OUTHILO>
__global__ __launch_bounds__(256)
void gemm_rt(const float* __restrict__ X, const float* __restrict__ W,
             const float* __restrict__ bias, float* __restrict__ Cf,
             ushort* __restrict__ Chi, ushort* __restrict__ Clo, int n)
{
    constexpr int TN = 128;
    constexpr int KC = 32;
    __shared__ float sXT[KC][128];
    __shared__ float sW[KC][TN];

    const int tid  = threadIdx.x;
    const int row0 = blockIdx.x * 128;
    const int rows = min(128, n - row0);
    if (rows <= 0) return;
    const int cg = tid % 16;
    const int rg = tid / 16;

    float acc[8][8] = {};

    for (int kc = 0; kc < K; kc += KC) {
        __syncthreads();
        for (int i = tid; i < KC * (TN / 4); i += 256) {
            int k = i / (TN / 4), c4 = i % (TN / 4);
            ((float4*)sW[k])[c4] = *(const float4*)&W[(size_t)(kc + k) * TN + c4 * 4];
        }
        for (int i = tid; i < (KC / 4) * 128; i += 256) {
            int r = i & 127, k4 = i >> 7;
            float4 v = {0.f, 0.f, 0.f, 0.f};
            if (r < rows) v = *(const float4*)&X[(size_t)(row0 + r) * K + kc + k4 * 4];
            sXT[k4 * 4 + 0][r] = v.x;
            sXT[k4 * 4 + 1][r] = v.y;
            sXT[k4 * 4 + 2][r] = v.z;
            sXT[k4 * 4 + 3][r] = v.w;
        }
        __syncthreads();
#pragma unroll 4
        for (int k = 0; k < KC; ++k) {
            float wv[8], xv[8];
            *(float4*)&wv[0] = *(const float4*)&sW[k][cg * 4];
            *(float4*)&wv[4] = *(const float4*)&sW[k][cg * 4 + 64];
            *(float4*)&xv[0] = *(const float4*)&sXT[k][rg * 4];
            *(float4*)&xv[4] = *(const float4*)&sXT[k][rg * 4 + 64];
#pragma unroll
            for (int i = 0; i < 8; ++i)
#pragma unroll
                for (int j = 0; j < 8; ++j)
                    acc[i][j] += xv[i] * wv[j];
        }
    }
#pragma unroll
    for (int i = 0; i < 8; ++i) {
        const int r = (i < 4) ? rg * 4 + i : 64 + rg * 4 + (i - 4);
        if (r < rows) {
#pragma unroll
            for (int half = 0; half < 2; ++half) {
                const int c = cg * 4 + half * 64;
                if (OUTHILO) {
                    ushort4 h4, l4;
                    ushort* hp = (ushort*)&h4; ushort* lp = (ushort*)&l4;
#pragma unroll
                    for (int j = 0; j < 4; ++j) {
                        float v = fmaxf(acc[i][half * 4 + j] + bias[c + j], 0.f);
                        split_bf(v, hp[j], lp[j]);
                    }
                    *(ushort4*)&Chi[(size_t)(row0 + r) * TN + c] = h4;
                    *(ushort4*)&Clo[(size_t)(row0 + r) * TN + c] = l4;
                } else {
                    float4 outv;
                    float* o = (float*)&outv;
#pragma unroll
                    for (int j = 0; j < 4; ++j)
                        o[j] = fmaxf(acc[i][half * 4 + j] + bias[c + j], 0.f);
                    *(float4*)&Cf[(size_t)(row0 + r) * TN + c] = outv;
                }
            }
        }
    }
}

// ============ weight transpose + split kernels ============
// msg_w[l]: [256][128] row-major; fused WT[l]: [256 cols][128 k] where
// col<128 -> W_top[k][col]=msg_w[k][col], col>=128 -> W_bot[k][col-128]=msg_w[128+k][col-128]
__global__ __launch_bounds__(256)
void tconv_msg(const float* __restrict__ W, ushort* __restrict__ Thi, ushort* __restrict__ Tlo)
{
    int idx = blockIdx.x * 256 + threadIdx.x;
    if (idx >= 3 * 32768) return;
    int l = idx >> 15, r = idx & 32767;
    int row = r >> 7, c = r & 127;
    int k, col;
    if (row < 128) { k = row; col = c; } else { k = row - 128; col = 128 + c; }
    ushort hi, lo;
    split_bf(W[idx], hi, lo);
    size_t o = (size_t)l * 32768 + (size_t)col * 128 + k;
    Thi[o] = hi; Tlo[o] = lo;
}

// lin_w[l]: [128][128] -> T[n][k]
__global__ __launch_bounds__(256)
void tconv_lin(const float* __restrict__ W, ushort* __restrict__ Thi, ushort* __restrict__ Tlo)
{
    int idx = blockIdx.x * 256 + threadIdx.x;
    if (idx >= 3 * 16384) return;
    int l = idx >> 14, r = idx & 16383;
    int k = r >> 7, nn = r & 127;
    ushort hi, lo;
    split_bf(W[idx], hi, lo);
    size_t o = (size_t)l * 16384 + (size_t)nn * 128 + k;
    Thi[o] = hi; Tlo[o] = lo;
}

// ============ CSR build ============
__global__ __launch_bounds__(256)
void hist_kernel(const int* __restrict__ idx, int* __restrict__ deg, int n)
{
    int i = blockIdx.x * 256 + threadIdx.x;
    if (i < n) atomicAdd(&deg[idx[i]], 1);
}

__global__ __launch_bounds__(256)
void scan_stage1(const int* __restrict__ in, int* __restrict__ excl,
                 int* __restrict__ partial, int n)
{
    const int tid = threadIdx.x;
    const int base = blockIdx.x * 1024 + tid * 4;
    int v[4];
    int s = 0;
#pragma unroll
    for (int i = 0; i < 4; ++i) {
        int t = (base + i < n) ? in[base + i] : 0;
        v[i] = s; s += t;
    }
    __shared__ int warpsum[4];
    const int lane = tid & 63, wid = tid >> 6;
    int pre = s;
#pragma unroll
    for (int off = 1; off < 64; off <<= 1) {
        int t = __shfl_up(pre, off);
        if (lane >= off) pre += t;
    }
    if (lane == 63) warpsum[wid] = pre;
    __syncthreads();
    int wo = 0;
    for (int w = 0; w < wid; ++w) wo += warpsum[w];
    const int thread_excl = wo + pre - s;
#pragma unroll
    for (int i = 0; i < 4; ++i)
        if (base + i < n) excl[base + i] = thread_excl + v[i];
    if (partial && tid == 255) partial[blockIdx.x] = wo + pre;
}

__global__ __launch_bounds__(256)
void scan_stage2(int* __restrict__ partial, int nb)
{
    __shared__ int tmp[256];
    const int tid = threadIdx.x;
    int v = (tid < nb) ? partial[tid] : 0;
    tmp[tid] = v;
    __syncthreads();
    for (int off = 1; off < 256; off <<= 1) {
        int t = (tid >= off) ? tmp[tid - off] : 0;
        __syncthreads();
        tmp[tid] += t;
        __syncthreads();
    }
    if (tid < nb) partial[tid] = tmp[tid] - v;
}

__global__ __launch_bounds__(256)
void scan_stage3(int* __restrict__ excl, const int* __restrict__ partial, int n)
{
    const int base = blockIdx.x * 1024 + threadIdx.x * 4;
    const int p = partial[blockIdx.x];
#pragma unroll
    for (int i = 0; i < 4; ++i)
        if (base + i < n) excl[base + i] += p;
}

__global__ __launch_bounds__(256)
void csr_fill(const int* __restrict__ src, const int* __restrict__ dst,
              const int* __restrict__ rowptr, int* __restrict__ cursor,
              int* __restrict__ csr_src, int E)
{
    int e = blockIdx.x * 256 + threadIdx.x;
    if (e >= E) return;
    int d = dst[e];
    int pos = atomicAdd(&cursor[d], 1);
    csr_src[rowptr[d] + pos] = src[e];
}

// ============ gather: aggr[v] = sum relu(AB[v][0:128] + AB[s][128:256] + mb) -> hi/lo ============
__global__ __launch_bounds__(256)
void gather_msg(const float* __restrict__ AB, const float* __restrict__ mb,
                const int* __restrict__ rowptr, const int* __restrict__ deg,
                const int* __restrict__ csr_src,
                ushort* __restrict__ AGhi, ushort* __restrict__ AGlo, int n)
{
    const int v = blockIdx.x * 8 + (threadIdx.x >> 5);
    if (v >= n) return;
    const int f = (threadIdx.x & 31) * 4;
    float4 a = *(const float4*)&AB[(size_t)v * 256 + f];
    float4 m = *(const float4*)&mb[f];
    const float ax = a.x + m.x, ay = a.y + m.y, az = a.z + m.z, aw = a.w + m.w;
    float4 acc = {0.f, 0.f, 0.f, 0.f};
    const int start = rowptr[v];
    const int cnt = deg[v];
    for (int i = 0; i < cnt; ++i) {
        int s = csr_src[start + i];
        float4 b = *(const float4*)&AB[(size_t)s * 256 + 128 + f];
        acc.x += fmaxf(ax + b.x, 0.f);
        acc.y += fmaxf(ay + b.y, 0.f);
        acc.z += fmaxf(az + b.z, 0.f);
        acc.w += fmaxf(aw + b.w, 0.f);
    }
    ushort4 h4, l4;
    ushort* hp = (ushort*)&h4; ushort* lp = (ushort*)&l4;
    split_bf(acc.x, hp[0], lp[0]);
    split_bf(acc.y, hp[1], lp[1]);
    split_bf(acc.z, hp[2], lp[2]);
    split_bf(acc.w, hp[3], lp[3]);
    *(ushort4*)&AGhi[(size_t)v * HIDDEN + f] = h4;
    *(ushort4*)&AGlo[(size_t)v * HIDDEN + f] = l4;
}

// ============ pooling ============
__global__ __launch_bounds__(128)
void pool_mean(const ushort* __restrict__ Hhi, const ushort* __restrict__ Hlo,
               const int* __restrict__ rp, const int* __restrict__ cnt,
               float* __restrict__ fused, int half)
{
    const int b = blockIdx.x;
    const int f = threadIdx.x;
    const int start = rp[b];
    const int c = cnt[b];
    float acc = 0.f;
    for (int i = 0; i < c; ++i) {
        size_t o = (size_t)(start + i) * HIDDEN + f;
        acc += bf2f(Hhi[o]) + bf2f(Hlo[o]);
    }
    fused[(size_t)b * (2 * HIDDEN) + half * HIDDEN + f] = acc / fmaxf((float)c, 1.0f);
}

// ============ head ============
__global__ __launch_bounds__(128)
void head_kernel(const float* __restrict__ fused,
                 const float* __restrict__ muw, const float* __restrict__ mub,
                 const float* __restrict__ lvw, const float* __restrict__ lvb,
                 float* __restrict__ mu, float* __restrict__ lv)
{
    __shared__ float sf[2 * HIDDEN];
    const int b = blockIdx.x;
    const int t = threadIdx.x;
    sf[t] = fused[(size_t)b * 256 + t];
    sf[t + 128] = fused[(size_t)b * 256 + t + 128];
    __syncthreads();
    if (t < ZDIM) {
        float accm = mub[t], accl = lvb[t];
        for (int k = 0; k < 2 * HIDDEN; ++k) {
            float fv = sf[k];
            accm += fv * muw[(size_t)k * ZDIM + t];
            accl += fv * lvw[(size_t)k * ZDIM + t];
        }
        mu[(size_t)b * ZDIM + t] = accm;
        lv[(size_t)b * ZDIM + t] = accl;
    }
}

extern "C" void kernel_launch(void* const* d_in, const int* in_sizes, int n_in,
                              void* d_out, int out_size, void* d_ws, size_t ws_size,
                              hipStream_t stream)
{
    const float* tree_x   = (const float*)d_in[0];
    const int*   tree_ei  = (const int*)d_in[1];
    const float* graph_x  = (const float*)d_in[2];
    const int*   graph_ei = (const int*)d_in[3];
    const int*   batch_t  = (const int*)d_in[4];
    const int*   batch_g  = (const int*)d_in[5];
    const float* t_proj_w = (const float*)d_in[6];
    const float* t_proj_b = (const float*)d_in[7];
    const float* t_msg_w  = (const float*)d_in[8];
    const float* t_msg_b  = (const float*)d_in[9];
    const float* t_lin_w  = (const float*)d_in[10];
    const float* t_lin_b  = (const float*)d_in[11];
    const float* g_proj_w = (const float*)d_in[12];
    const float* g_proj_b = (const float*)d_in[13];
    const float* g_msg_w  = (const float*)d_in[14];
    const float* g_msg_b  = (const float*)d_in[15];
    const float* g_lin_w  = (const float*)d_in[16];
    const float* g_lin_b  = (const float*)d_in[17];
    const float* mu_w     = (const float*)d_in[18];
    const float* mu_b     = (const float*)d_in[19];
    const float* lv_w     = (const float*)d_in[20];
    const float* lv_b     = (const float*)d_in[21];

    const int n_tree  = in_sizes[0] / 64;
    const int e_tree  = in_sizes[1] / 2;
    const int n_graph = in_sizes[2] / 32;
    const int e_graph = in_sizes[3] / 2;

    float* out    = (float*)d_out;
    float* mu_out = out;
    float* lv_out = out + (size_t)NGRAPHS * ZDIM;
    float* fused  = out + (size_t)2 * NGRAPHS * ZDIM;

    // ---- workspace carve (byte-based) ----
    char* base = (char*)d_ws;
    const size_t nmax = (size_t)n_graph;
    float*  AB   = (float*)base;  base += nmax * 256 * sizeof(float);
    ushort* Hhi  = (ushort*)base; base += nmax * 128 * sizeof(ushort);
    ushort* Hlo  = (ushort*)base; base += nmax * 128 * sizeof(ushort);
    ushort* WThi = (ushort*)base; base += (size_t)3 * 32768 * sizeof(ushort);
    ushort* WTlo = (ushort*)base; base += (size_t)3 * 32768 * sizeof(ushort);
    ushort* LThi = (ushort*)base; base += (size_t)3 * 16384 * sizeof(ushort);
    ushort* LTlo = (ushort*)base; base += (size_t)3 * 16384 * sizeof(ushort);
    int* deg     = (int*)base;    base += (size_t)n_graph * sizeof(int);
    int* rowptr  = (int*)base;    base += (size_t)n_graph * sizeof(int);
    int* cursor  = (int*)base;    base += (size_t)n_graph * sizeof(int);
    int* csr_src = (int*)base;    base += (size_t)e_graph * sizeof(int);
    int* partial = (int*)base;    base += 256 * sizeof(int);
    int* degb    = (int*)base;    base += NGRAPHS * sizeof(int);
    int* rpb     = (int*)base;

    auto run_encoder = [&](const float* x, int Kin, int n, int E, const int* ei,
                           const int* batch,
                           const float* proj_w, const float* proj_b,
                           const float* msg_w, const float* msg_b,
                           const float* lin_w, const float* lin_b, int half) {
        const int nb = (n + 1023) / 1024;
        const int gb64 = (n + 63) / 64;
        const int* src = ei;        // edge_index[0]  (x_j)
        const int* dst = ei + E;    // edge_index[1]  (x_i / aggregation target)

        // ---- CSR build ----
        hipMemsetAsync(deg, 0, (size_t)n * sizeof(int), stream);
        hipMemsetAsync(cursor, 0, (size_t)n * sizeof(int), stream);
        hist_kernel<<<(E + 255) / 256, 256, 0, stream>>>(dst, deg, E);
        scan_stage1<<<nb, 256, 0, stream>>>(deg, rowptr, partial, n);
        scan_stage2<<<1, 256, 0, stream>>>(partial, nb);
        scan_stage3<<<nb, 256, 0, stream>>>(rowptr, partial, n);
        csr_fill<<<(E + 255) / 256, 256, 0, stream>>>(src, dst, rowptr, cursor, csr_src, E);

        // ---- batch ranges (batch sorted) ----
        hipMemsetAsync(degb, 0, NGRAPHS * sizeof(int), stream);
        hist_kernel<<<(n + 255) / 256, 256, 0, stream>>>(batch, degb, n);
        scan_stage1<<<1, 256, 0, stream>>>(degb, rpb, nullptr, NGRAPHS);

        // ---- weight transpose + split ----
        tconv_msg<<<(3 * 32768 + 255) / 256, 256, 0, stream>>>(msg_w, WThi, WTlo);
        tconv_lin<<<(3 * 16384 + 255) / 256, 256, 0, stream>>>(lin_w, LThi, LTlo);

        // ---- input projection -> h hi/lo ----
        if (Kin == 64)
            gemm_rt<64, true><<<(n + 127) / 128, 256, 0, stream>>>(
                x, proj_w, proj_b, nullptr, Hhi, Hlo, n);
        else
            gemm_rt<32, true><<<(n + 127) / 128, 256, 0, stream>>>(
                x, proj_w, proj_b, nullptr, Hhi, Hlo, n);

        for (int l = 0; l < NLAYERS; ++l) {
            // AB = h @ [W_top | W_bot]  -> f32 [n, 256]
            gemm_mfma<256, false, false, false><<<gb64, 256, 0, stream>>>(
                Hhi, Hlo, WThi + (size_t)l * 32768, WTlo + (size_t)l * 32768,
                nullptr, AB, nullptr, nullptr, n);
            // aggr -> hi/lo (overwrites h planes; h is dead)
            gather_msg<<<(n + 7) / 8, 256, 0, stream>>>(
                AB, msg_b + (size_t)l * HIDDEN, rowptr, deg, csr_src, Hhi, Hlo, n);
            // h' = relu(aggr @ lin + b) -> hi/lo in place
            gemm_mfma<128, true, true, true><<<gb64, 256, 0, stream>>>(
                Hhi, Hlo, LThi + (size_t)l * 16384, LTlo + (size_t)l * 16384,
                lin_b + (size_t)l * HIDDEN, nullptr, Hhi, Hlo, n);
        }
        pool_mean<<<NGRAPHS, 128, 0, stream>>>(Hhi, Hlo, rpb, degb, fused, half);
    };

    run_encoder(tree_x, 64, n_tree, e_tree, tree_ei, batch_t,
                t_proj_w, t_proj_b, t_msg_w, t_msg_b, t_lin_w, t_lin_b, 0);
    run_encoder(graph_x, 32, n_graph, e_graph, graph_ei, batch_g,
                g_proj_w, g_proj_b, g_msg_w, g_msg_b, g_lin_w, g_lin_b, 1);

    head_kernel<<<NGRAPHS, 128, 0, stream>>>(fused, mu_w, mu_b, lv_w, lv_b, mu_out, lv_out);
}

// Round 7
// 889.537 us; speedup vs baseline: 3.7624x; 1.0549x over previous
//
#include <hip/hip_runtime.h>

#define HIDDEN 128
#define ZDIM 56
#define NLAYERS 3
#define NGRAPHS 1024

typedef __attribute__((ext_vector_type(8))) short short8v;
typedef __attribute__((ext_vector_type(4))) float float4v;

__device__ __forceinline__ ushort f2bf(float v) {
    union { float f; unsigned u; } x; x.f = v;
    unsigned r = x.u + 0x7fffu + ((x.u >> 16) & 1u);   // RNE
    return (ushort)(r >> 16);
}
__device__ __forceinline__ float bf2f(ushort h) {
    union { unsigned u; float f; } x; x.u = ((unsigned)h) << 16;
    return x.f;
}
__device__ __forceinline__ void split_bf(float v, ushort& hi, ushort& lo) {
    hi = f2bf(v);
    lo = f2bf(v - bf2f(hi));
}
__device__ __forceinline__ void gload_lds16(const void* g, void* l) {
    __builtin_amdgcn_global_load_lds(
        (const __attribute__((address_space(1))) unsigned int*)g,
        (__attribute__((address_space(3))) unsigned int*)l, 16, 0, 0);
}

// ============ split-bf16 MFMA GEMM: C[n x TN] = act(X[n x 128] @ W[128 x TN] (+bias)) ============
// X as hi/lo bf16 planes [n][128]; W TRANSPOSED as hi/lo [TN][128].
// Block 512 thr / 8 waves; tile M=128. Wave w: row-half wr=w>>2 (64 rows), col group wc=w&3
// (CPW 16-col frags). LDS cell layout (16B cells, linear so global_load_lds writes it):
//   X: cell c = plane*512 + sg*128 + r       -> [plane][sg][r][8 bf16]
//   W: cell c = plane*4*TN + sg*TN + col     -> [plane][sg][col][8 bf16]
// 3 MFMAs per (hi,lo) pair: ah*bh + ah*bl + al*bh  (al*bl ~2^-18, dropped).
template<int TN, bool RELU, bool BIAS, bool OUTHILO>
__global__ __launch_bounds__(512, 4)
void gemm_mfma(const ushort* __restrict__ Xhi, const ushort* __restrict__ Xlo,
               const ushort* __restrict__ WThi, const ushort* __restrict__ WTlo,
               const float* __restrict__ bias,
               float* __restrict__ Cf, ushort* __restrict__ Chi, ushort* __restrict__ Clo,
               int n)
{
    constexpr int K = 128;
    constexpr int CPW = TN / 64;            // col frags per wave
    constexpr int XCELLS = 2 * 4 * 128;     // 1024 16B-cells
    constexpr int WCELLS = 2 * 4 * TN;      // 2048 (TN=256) / 1024 (TN=128)
    __shared__ ushort smem[(XCELLS + WCELLS) * 8];
    ushort* sX = smem;
    ushort* sW = smem + XCELLS * 8;

    const int tid = threadIdx.x;
    const int w = tid >> 6, l = tid & 63;
    const int wr = w >> 2;                  // row half
    const int wc = w & 3;                   // col group
    const int seg = l >> 4, lr = l & 15;
    const int row0 = blockIdx.x * 128;
    if (row0 >= n) return;
    const bool fulltile = (row0 + 128 <= n);

    float4v acc[4][CPW];
#pragma unroll
    for (int i = 0; i < 4; ++i)
#pragma unroll
        for (int j = 0; j < CPW; ++j) {
            float4v z = {0.f, 0.f, 0.f, 0.f};
            acc[i][j] = z;
        }

    for (int kc = 0; kc < K; kc += 32) {
        __syncthreads();
        // ---- stage X (1024 cells) ----
        if (fulltile) {
#pragma unroll
            for (int t = 0; t < XCELLS / 512; ++t) {
                const int cbase = (w * (XCELLS / 512) + t) * 64;
                const int c = cbase + l;
                const int plane = c >> 9, rem = c & 511, sg = rem >> 7, r = rem & 127;
                const ushort* srcp = plane ? Xlo : Xhi;
                gload_lds16(&srcp[(size_t)(row0 + r) * K + kc + sg * 8],
                            (char*)sX + (size_t)cbase * 16);
            }
        } else {
            for (int c = tid; c < XCELLS; c += 512) {
                const int plane = c >> 9, rem = c & 511, sg = rem >> 7, r = rem & 127;
                const ushort* srcp = plane ? Xlo : Xhi;
                short8v v = {0, 0, 0, 0, 0, 0, 0, 0};
                if (row0 + r < n)
                    v = *(const short8v*)&srcp[(size_t)(row0 + r) * K + kc + sg * 8];
                *(short8v*)&sX[(size_t)c * 8] = v;
            }
        }
        // ---- stage W (WCELLS cells) ----
#pragma unroll
        for (int t = 0; t < WCELLS / 512; ++t) {
            const int cbase = (w * (WCELLS / 512) + t) * 64;
            const int c = cbase + l;
            const int plane = (c >= WCELLS / 2) ? 1 : 0;
            const int rem = c - plane * (WCELLS / 2);
            const int sg = rem / TN, col = rem % TN;
            const ushort* srcp = plane ? WTlo : WThi;
            gload_lds16(&srcp[(size_t)col * K + kc + sg * 8],
                        (char*)sW + (size_t)cbase * 16);
        }
        __syncthreads();

        short8v ah[4], al[4];
#pragma unroll
        for (int i = 0; i < 4; ++i) {
            const int off = (seg * 128 + wr * 64 + i * 16 + lr) * 8;
            ah[i] = *(const short8v*)&sX[off];
            al[i] = *(const short8v*)&sX[(XCELLS / 2) * 8 + off];
        }
#pragma unroll
        for (int j = 0; j < CPW; ++j) {
            const int col = (wc * CPW + j) * 16 + lr;
            const int off = (seg * TN + col) * 8;
            short8v bh = *(const short8v*)&sW[off];
            short8v bl = *(const short8v*)&sW[(WCELLS / 2) * 8 + off];
#pragma unroll
            for (int i = 0; i < 4; ++i) {
                acc[i][j] = __builtin_amdgcn_mfma_f32_16x16x32_bf16(ah[i], bh, acc[i][j], 0, 0, 0);
                acc[i][j] = __builtin_amdgcn_mfma_f32_16x16x32_bf16(ah[i], bl, acc[i][j], 0, 0, 0);
                acc[i][j] = __builtin_amdgcn_mfma_f32_16x16x32_bf16(al[i], bh, acc[i][j], 0, 0, 0);
            }
        }
    }

    // epilogue: D[row = seg*4 + rr][col = lr] within each 16x16 frag
#pragma unroll
    for (int i = 0; i < 4; ++i) {
#pragma unroll
        for (int j = 0; j < CPW; ++j) {
            const int gcol = (wc * CPW + j) * 16 + lr;
            const float bv = BIAS ? bias[gcol] : 0.f;
#pragma unroll
            for (int r = 0; r < 4; ++r) {
                const int grow = row0 + wr * 64 + i * 16 + seg * 4 + r;
                if (grow < n) {
                    float v = acc[i][j][r] + bv;
                    if (RELU) v = fmaxf(v, 0.f);
                    if (OUTHILO) {
                        ushort hi, lo;
                        split_bf(v, hi, lo);
                        Chi[(size_t)grow * TN + gcol] = hi;
                        Clo[(size_t)grow * TN + gcol] = lo;
                    } else {
                        Cf[(size_t)grow * TN + gcol] = v;
                    }
                }
            }
        }
    }
}

// ============ f32 vector GEMM for input projection (K=32/64), TN=128 ============
template<int K, bool OUTHILO>
__global__ __launch_bounds__(256)
void gemm_rt(const float* __restrict__ X, const float* __restrict__ W,
             const float* __restrict__ bias, float* __restrict__ Cf,
             ushort* __restrict__ Chi, ushort* __restrict__ Clo, int n)
{
    constexpr int TN = 128;
    constexpr int KC = 32;
    __shared__ float sXT[KC][128];
    __shared__ float sW[KC][TN];

    const int tid  = threadIdx.x;
    const int row0 = blockIdx.x * 128;
    const int rows = min(128, n - row0);
    if (rows <= 0) return;
    const int cg = tid % 16;
    const int rg = tid / 16;

    float acc[8][8] = {};

    for (int kc = 0; kc < K; kc += KC) {
        __syncthreads();
        for (int i = tid; i < KC * (TN / 4); i += 256) {
            int k = i / (TN / 4), c4 = i % (TN / 4);
            ((float4*)sW[k])[c4] = *(const float4*)&W[(size_t)(kc + k) * TN + c4 * 4];
        }
        for (int i = tid; i < (KC / 4) * 128; i += 256) {
            int r = i & 127, k4 = i >> 7;
            float4 v = {0.f, 0.f, 0.f, 0.f};
            if (r < rows) v = *(const float4*)&X[(size_t)(row0 + r) * K + kc + k4 * 4];
            sXT[k4 * 4 + 0][r] = v.x;
            sXT[k4 * 4 + 1][r] = v.y;
            sXT[k4 * 4 + 2][r] = v.z;
            sXT[k4 * 4 + 3][r] = v.w;
        }
        __syncthreads();
#pragma unroll 4
        for (int k = 0; k < KC; ++k) {
            float wv[8], xv[8];
            *(float4*)&wv[0] = *(const float4*)&sW[k][cg * 4];
            *(float4*)&wv[4] = *(const float4*)&sW[k][cg * 4 + 64];
            *(float4*)&xv[0] = *(const float4*)&sXT[k][rg * 4];
            *(float4*)&xv[4] = *(const float4*)&sXT[k][rg * 4 + 64];
#pragma unroll
            for (int i = 0; i < 8; ++i)
#pragma unroll
                for (int j = 0; j < 8; ++j)
                    acc[i][j] += xv[i] * wv[j];
        }
    }
#pragma unroll
    for (int i = 0; i < 8; ++i) {
        const int r = (i < 4) ? rg * 4 + i : 64 + rg * 4 + (i - 4);
        if (r < rows) {
#pragma unroll
            for (int half = 0; half < 2; ++half) {
                const int c = cg * 4 + half * 64;
                if (OUTHILO) {
                    ushort4 h4, l4;
                    ushort* hp = (ushort*)&h4; ushort* lp = (ushort*)&l4;
#pragma unroll
                    for (int j = 0; j < 4; ++j) {
                        float v = fmaxf(acc[i][half * 4 + j] + bias[c + j], 0.f);
                        split_bf(v, hp[j], lp[j]);
                    }
                    *(ushort4*)&Chi[(size_t)(row0 + r) * TN + c] = h4;
                    *(ushort4*)&Clo[(size_t)(row0 + r) * TN + c] = l4;
                } else {
                    float4 outv;
                    float* o = (float*)&outv;
#pragma unroll
                    for (int j = 0; j < 4; ++j)
                        o[j] = fmaxf(acc[i][half * 4 + j] + bias[c + j], 0.f);
                    *(float4*)&Cf[(size_t)(row0 + r) * TN + c] = outv;
                }
            }
        }
    }
}

// ============ fused weight transpose + split ============
// msg_w[l]: [256][128] row-major -> WT[l]: [256 cols][128 k]
//   (col<128 -> W_top[k][col], col>=128 -> W_bot[k][col-128])
// lin_w[l]: [128][128] -> LT[l][n][k]
__global__ __launch_bounds__(256)
void tconv_all(const float* __restrict__ MW, const float* __restrict__ LW,
               ushort* __restrict__ WThi, ushort* __restrict__ WTlo,
               ushort* __restrict__ LThi, ushort* __restrict__ LTlo)
{
    int idx = blockIdx.x * 256 + threadIdx.x;
    if (idx < 3 * 32768) {
        int l = idx >> 15, r = idx & 32767;
        int row = r >> 7, c = r & 127;
        int k, col;
        if (row < 128) { k = row; col = c; } else { k = row - 128; col = 128 + c; }
        ushort hi, lo;
        split_bf(MW[idx], hi, lo);
        size_t o = (size_t)l * 32768 + (size_t)col * 128 + k;
        WThi[o] = hi; WTlo[o] = lo;
    } else {
        int j = idx - 3 * 32768;
        if (j >= 3 * 16384) return;
        int l = j >> 14, r = j & 16383;
        int k = r >> 7, nn = r & 127;
        ushort hi, lo;
        split_bf(LW[j], hi, lo);
        size_t o = (size_t)l * 16384 + (size_t)nn * 128 + k;
        LThi[o] = hi; LTlo[o] = lo;
    }
}

// ============ CSR build ============
__global__ __launch_bounds__(256)
void hist_kernel(const int* __restrict__ idx, int* __restrict__ deg, int n)
{
    int i = blockIdx.x * 256 + threadIdx.x;
    if (i < n) atomicAdd(&deg[idx[i]], 1);
}

__global__ __launch_bounds__(256)
void scan_stage1(const int* __restrict__ in, int* __restrict__ excl,
                 int* __restrict__ partial, int n)
{
    const int tid = threadIdx.x;
    const int base = blockIdx.x * 1024 + tid * 4;
    int v[4];
    int s = 0;
#pragma unroll
    for (int i = 0; i < 4; ++i) {
        int t = (base + i < n) ? in[base + i] : 0;
        v[i] = s; s += t;
    }
    __shared__ int warpsum[4];
    const int lane = tid & 63, wid = tid >> 6;
    int pre = s;
#pragma unroll
    for (int off = 1; off < 64; off <<= 1) {
        int t = __shfl_up(pre, off);
        if (lane >= off) pre += t;
    }
    if (lane == 63) warpsum[wid] = pre;
    __syncthreads();
    int wo = 0;
    for (int w = 0; w < wid; ++w) wo += warpsum[w];
    const int thread_excl = wo + pre - s;
#pragma unroll
    for (int i = 0; i < 4; ++i)
        if (base + i < n) excl[base + i] = thread_excl + v[i];
    if (partial && tid == 255) partial[blockIdx.x] = wo + pre;
}

__global__ __launch_bounds__(256)
void scan_stage2(int* __restrict__ partial, int nb)
{
    __shared__ int tmp[256];
    const int tid = threadIdx.x;
    int v = (tid < nb) ? partial[tid] : 0;
    tmp[tid] = v;
    __syncthreads();
    for (int off = 1; off < 256; off <<= 1) {
        int t = (tid >= off) ? tmp[tid - off] : 0;
        __syncthreads();
        tmp[tid] += t;
        __syncthreads();
    }
    if (tid < nb) partial[tid] = tmp[tid] - v;
}

__global__ __launch_bounds__(256)
void scan_stage3(int* __restrict__ excl, const int* __restrict__ partial, int n)
{
    const int base = blockIdx.x * 1024 + threadIdx.x * 4;
    const int p = partial[blockIdx.x];
#pragma unroll
    for (int i = 0; i < 4; ++i)
        if (base + i < n) excl[base + i] += p;
}

__global__ __launch_bounds__(256)
void csr_fill(const int* __restrict__ src, const int* __restrict__ dst,
              const int* __restrict__ rowptr, int* __restrict__ cursor,
              int* __restrict__ csr_src, int E)
{
    int e = blockIdx.x * 256 + threadIdx.x;
    if (e >= E) return;
    int d = dst[e];
    int pos = atomicAdd(&cursor[d], 1);
    csr_src[rowptr[d] + pos] = src[e];
}

// ============ gather: aggr[v] = sum relu(AB[v][0:128] + AB[s][128:256] + mb) -> hi/lo ============
__global__ __launch_bounds__(256)
void gather_msg(const float* __restrict__ AB, const float* __restrict__ mb,
                const int* __restrict__ rowptr, const int* __restrict__ deg,
                const int* __restrict__ csr_src,
                ushort* __restrict__ AGhi, ushort* __restrict__ AGlo, int n)
{
    const int v = blockIdx.x * 8 + (threadIdx.x >> 5);
    if (v >= n) return;
    const int f = (threadIdx.x & 31) * 4;
    float4 a = *(const float4*)&AB[(size_t)v * 256 + f];
    float4 m = *(const float4*)&mb[f];
    const float ax = a.x + m.x, ay = a.y + m.y, az = a.z + m.z, aw = a.w + m.w;
    float4 acc = {0.f, 0.f, 0.f, 0.f};
    const int start = rowptr[v];
    const int cnt = deg[v];
    for (int i = 0; i < cnt; ++i) {
        int s = csr_src[start + i];
        float4 b = *(const float4*)&AB[(size_t)s * 256 + 128 + f];
        acc.x += fmaxf(ax + b.x, 0.f);
        acc.y += fmaxf(ay + b.y, 0.f);
        acc.z += fmaxf(az + b.z, 0.f);
        acc.w += fmaxf(aw + b.w, 0.f);
    }
    ushort4 h4, l4;
    ushort* hp = (ushort*)&h4; ushort* lp = (ushort*)&l4;
    split_bf(acc.x, hp[0], lp[0]);
    split_bf(acc.y, hp[1], lp[1]);
    split_bf(acc.z, hp[2], lp[2]);
    split_bf(acc.w, hp[3], lp[3]);
    *(ushort4*)&AGhi[(size_t)v * HIDDEN + f] = h4;
    *(ushort4*)&AGlo[(size_t)v * HIDDEN + f] = l4;
}

// ============ pooling ============
__global__ __launch_bounds__(128)
void pool_mean(const ushort* __restrict__ Hhi, const ushort* __restrict__ Hlo,
               const int* __restrict__ rp, const int* __restrict__ cnt,
               float* __restrict__ fused, int half)
{
    const int b = blockIdx.x;
    const int f = threadIdx.x;
    const int start = rp[b];
    const int c = cnt[b];
    float acc = 0.f;
    for (int i = 0; i < c; ++i) {
        size_t o = (size_t)(start + i) * HIDDEN + f;
        acc += bf2f(Hhi[o]) + bf2f(Hlo[o]);
    }
    fused[(size_t)b * (2 * HIDDEN) + half * HIDDEN + f] = acc / fmaxf((float)c, 1.0f);
}

// ============ head ============
__global__ __launch_bounds__(128)
void head_kernel(const float* __restrict__ fused,
                 const float* __restrict__ muw, const float* __restrict__ mub,
                 const float* __restrict__ lvw, const float* __restrict__ lvb,
                 float* __restrict__ mu, float* __restrict__ lv)
{
    __shared__ float sf[2 * HIDDEN];
    const int b = blockIdx.x;
    const int t = threadIdx.x;
    sf[t] = fused[(size_t)b * 256 + t];
    sf[t + 128] = fused[(size_t)b * 256 + t + 128];
    __syncthreads();
    if (t < ZDIM) {
        float accm = mub[t], accl = lvb[t];
        for (int k = 0; k < 2 * HIDDEN; ++k) {
            float fv = sf[k];
            accm += fv * muw[(size_t)k * ZDIM + t];
            accl += fv * lvw[(size_t)k * ZDIM + t];
        }
        mu[(size_t)b * ZDIM + t] = accm;
        lv[(size_t)b * ZDIM + t] = accl;
    }
}

extern "C" void kernel_launch(void* const* d_in, const int* in_sizes, int n_in,
                              void* d_out, int out_size, void* d_ws, size_t ws_size,
                              hipStream_t stream)
{
    const float* tree_x   = (const float*)d_in[0];
    const int*   tree_ei  = (const int*)d_in[1];
    const float* graph_x  = (const float*)d_in[2];
    const int*   graph_ei = (const int*)d_in[3];
    const int*   batch_t  = (const int*)d_in[4];
    const int*   batch_g  = (const int*)d_in[5];
    const float* t_proj_w = (const float*)d_in[6];
    const float* t_proj_b = (const float*)d_in[7];
    const float* t_msg_w  = (const float*)d_in[8];
    const float* t_msg_b  = (const float*)d_in[9];
    const float* t_lin_w  = (const float*)d_in[10];
    const float* t_lin_b  = (const float*)d_in[11];
    const float* g_proj_w = (const float*)d_in[12];
    const float* g_proj_b = (const float*)d_in[13];
    const float* g_msg_w  = (const float*)d_in[14];
    const float* g_msg_b  = (const float*)d_in[15];
    const float* g_lin_w  = (const float*)d_in[16];
    const float* g_lin_b  = (const float*)d_in[17];
    const float* mu_w     = (const float*)d_in[18];
    const float* mu_b     = (const float*)d_in[19];
    const float* lv_w     = (const float*)d_in[20];
    const float* lv_b     = (const float*)d_in[21];

    const int n_tree  = in_sizes[0] / 64;
    const int e_tree  = in_sizes[1] / 2;
    const int n_graph = in_sizes[2] / 32;
    const int e_graph = in_sizes[3] / 2;

    float* out    = (float*)d_out;
    float* mu_out = out;
    float* lv_out = out + (size_t)NGRAPHS * ZDIM;
    float* fused  = out + (size_t)2 * NGRAPHS * ZDIM;

    // ---- workspace carve (byte-based) ----
    char* base = (char*)d_ws;
    const size_t nmax = (size_t)n_graph;
    float*  AB   = (float*)base;  base += nmax * 256 * sizeof(float);
    ushort* Hhi  = (ushort*)base; base += nmax * 128 * sizeof(ushort);
    ushort* Hlo  = (ushort*)base; base += nmax * 128 * sizeof(ushort);
    ushort* WThi = (ushort*)base; base += (size_t)3 * 32768 * sizeof(ushort);
    ushort* WTlo = (ushort*)base; base += (size_t)3 * 32768 * sizeof(ushort);
    ushort* LThi = (ushort*)base; base += (size_t)3 * 16384 * sizeof(ushort);
    ushort* LTlo = (ushort*)base; base += (size_t)3 * 16384 * sizeof(ushort);
    int* deg     = (int*)base;    base += nmax * sizeof(int);   // deg, cursor, degb contiguous
    int* cursor  = (int*)base;    base += nmax * sizeof(int);   //   (stride nmax!) -> single memset
    int* degb    = (int*)base;    base += NGRAPHS * sizeof(int);
    int* rowptr  = (int*)base;    base += nmax * sizeof(int);
    int* csr_src = (int*)base;    base += (size_t)e_graph * sizeof(int);
    int* partial = (int*)base;    base += 256 * sizeof(int);
    int* rpb     = (int*)base;

    auto run_encoder = [&](const float* x, int Kin, int n, int E, const int* ei,
                           const int* batch,
                           const float* proj_w, const float* proj_b,
                           const float* msg_w, const float* msg_b,
                           const float* lin_w, const float* lin_b, int half) {
        const int nb = (n + 1023) / 1024;
        const int gb128 = (n + 127) / 128;
        const int* src = ei;        // edge_index[0]  (x_j)
        const int* dst = ei + E;    // edge_index[1]  (x_i / aggregation target)

        // ---- CSR build ----
        // NOTE: deg/cursor are carved with stride nmax (= n_graph), NOT n.
        // Memset must cover the full carve: deg[nmax] + cursor[nmax] + degb[NGRAPHS].
        hipMemsetAsync(deg, 0, (2 * nmax + NGRAPHS) * sizeof(int), stream);
        hist_kernel<<<(E + 255) / 256, 256, 0, stream>>>(dst, deg, E);
        scan_stage1<<<nb, 256, 0, stream>>>(deg, rowptr, partial, n);
        scan_stage2<<<1, 256, 0, stream>>>(partial, nb);
        scan_stage3<<<nb, 256, 0, stream>>>(rowptr, partial, n);
        csr_fill<<<(E + 255) / 256, 256, 0, stream>>>(src, dst, rowptr, cursor, csr_src, E);

        // ---- batch ranges (batch sorted) ----
        hist_kernel<<<(n + 255) / 256, 256, 0, stream>>>(batch, degb, n);
        scan_stage1<<<1, 256, 0, stream>>>(degb, rpb, nullptr, NGRAPHS);

        // ---- weight transpose + split (fused) ----
        tconv_all<<<(3 * 32768 + 3 * 16384 + 255) / 256, 256, 0, stream>>>(
            msg_w, lin_w, WThi, WTlo, LThi, LTlo);

        // ---- input projection -> h hi/lo ----
        if (Kin == 64)
            gemm_rt<64, true><<<gb128, 256, 0, stream>>>(
                x, proj_w, proj_b, nullptr, Hhi, Hlo, n);
        else
            gemm_rt<32, true><<<gb128, 256, 0, stream>>>(
                x, proj_w, proj_b, nullptr, Hhi, Hlo, n);

        for (int l = 0; l < NLAYERS; ++l) {
            // AB = h @ [W_top | W_bot]  -> f32 [n, 256]
            gemm_mfma<256, false, false, false><<<gb128, 512, 0, stream>>>(
                Hhi, Hlo, WThi + (size_t)l * 32768, WTlo + (size_t)l * 32768,
                nullptr, AB, nullptr, nullptr, n);
            // aggr -> hi/lo (overwrites h planes; h is dead)
            gather_msg<<<(n + 7) / 8, 256, 0, stream>>>(
                AB, msg_b + (size_t)l * HIDDEN, rowptr, deg, csr_src, Hhi, Hlo, n);
            // h' = relu(aggr @ lin + b) -> hi/lo in place
            gemm_mfma<128, true, true, true><<<gb128, 512, 0, stream>>>(
                Hhi, Hlo, LThi + (size_t)l * 16384, LTlo + (size_t)l * 16384,
                lin_b + (size_t)l * HIDDEN, nullptr, Hhi, Hlo, n);
        }
        pool_mean<<<NGRAPHS, 128, 0, stream>>>(Hhi, Hlo, rpb, degb, fused, half);
    };

    run_encoder(tree_x, 64, n_tree, e_tree, tree_ei, batch_t,
                t_proj_w, t_proj_b, t_msg_w, t_msg_b, t_lin_w, t_lin_b, 0);
    run_encoder(graph_x, 32, n_graph, e_graph, graph_ei, batch_g,
                g_proj_w, g_proj_b, g_msg_w, g_msg_b, g_lin_w, g_lin_b, 1);

    head_kernel<<<NGRAPHS, 128, 0, stream>>>(fused, mu_w, mu_b, lv_w, lv_b, mu_out, lv_out);
}